// Round 1
// baseline (1087.577 us; speedup 1.0000x reference)
//
#include <hip/hip_runtime.h>

#define TE 64      // edges per tile (kernel A)
#define TN 64      // nodes per tile (kernel B)
#define PADE 4     // LDS column padding (16B-aligned)

union F4 { float4 v; float f[4]; };

__device__ __forceinline__ float gelu_f(float x) {
    // jax.nn.gelu(approximate=True): 0.5*x*(1+tanh(sqrt(2/pi)*(x+0.044715*x^3)))
    const float c0 = 0.7978845608028654f;
    float z = c0 * (x + 0.044715f * x * x * x);
    // tanh(z) = 1 - 2/(exp(2z)+1); exp(2z) = exp2(2z*log2(e))
    float ez = __builtin_exp2f(z * 2.8853900817779268f);
    float th = 1.0f - 2.0f * __builtin_amdgcn_rcpf(ez + 1.0f);
    return 0.5f * x * (1.0f + th);
}

// ---------------- Kernel A: edge MLP + scatter-add ----------------
__global__ __launch_bounds__(256) void edge_mlp_kernel(
    const float* __restrict__ nf,   // [N,64]
    const float* __restrict__ ef,   // [E,16]
    const int*   __restrict__ ei,   // [2,E] int32
    const float* __restrict__ W1,   // [80,64]
    const float* __restrict__ b1,   // [64]
    const float* __restrict__ W2,   // [64,64]
    const float* __restrict__ b2,   // [64]
    float*       __restrict__ agg,  // [N,64] (pre-zeroed)
    int nE, int nTiles)
{
    __shared__ float sW1[80][64];
    __shared__ float sW2[64][64];
    __shared__ float sX[80][TE + PADE];   // x transposed: [k][e]
    __shared__ float sM[64][TE + PADE];   // gelu(msg1) transposed: [c][e]
    __shared__ int   sDst[TE];

    const int t = threadIdx.x;

    // stage weights once per block
    for (int i = t * 4; i < 80 * 64; i += 1024)
        *(float4*)((float*)sW1 + i) = *(const float4*)(W1 + i);
    for (int i = t * 4; i < 64 * 64; i += 1024)
        *(float4*)((float*)sW2 + i) = *(const float4*)(W2 + i);

    const int lane = t & 63;
    const int w    = t >> 6;          // wave id 0..3
    const int e0   = (t & 15) * 4;    // microtile edges
    const int c0   = (t >> 4) * 4;    // microtile channels
    F4 b1v, b2v;
    b1v.v = *(const float4*)(b1 + c0);
    b2v.v = *(const float4*)(b2 + c0);

    for (int tile = blockIdx.x; tile < nTiles; tile += gridDim.x) {
        const int gbase = tile * TE;
        // ---- gather: edge (=lane) x feature-chunk (=wave) ----
        {
            int ge = gbase + lane;
            if (ge >= nE) ge = nE - 1;              // clamp (tail-safe)
            const int src = ei[ge];
            const float4* nrow = (const float4*)(nf + (size_t)src * 64);
            F4 a0, a1, a2, a3, ev;
            a0.v = nrow[w * 4 + 0];
            a1.v = nrow[w * 4 + 1];
            a2.v = nrow[w * 4 + 2];
            a3.v = nrow[w * 4 + 3];
            ev.v = *(const float4*)(ef + (size_t)ge * 16 + w * 4);
            const int kb = w * 16;
            #pragma unroll
            for (int j = 0; j < 4; ++j) {
                sX[kb + 0  + j][lane] = a0.f[j];
                sX[kb + 4  + j][lane] = a1.f[j];
                sX[kb + 8  + j][lane] = a2.f[j];
                sX[kb + 12 + j][lane] = a3.f[j];
                sX[64 + w * 4 + j][lane] = ev.f[j];
            }
            if (w == 0) sDst[lane] = ei[nE + ge];
        }
        __syncthreads();

        // ---- GEMM1: [64e x 80] @ [80 x 64c] ----
        float acc[4][4] = {};
        #pragma unroll 8
        for (int k = 0; k < 80; ++k) {
            F4 xv, wv;
            xv.v = *(const float4*)&sX[k][e0];
            wv.v = *(const float4*)&sW1[k][c0];
            #pragma unroll
            for (int i = 0; i < 4; ++i)
                #pragma unroll
                for (int j = 0; j < 4; ++j)
                    acc[i][j] = fmaf(xv.f[i], wv.f[j], acc[i][j]);
        }
        // gelu + write transposed msg1
        #pragma unroll
        for (int j = 0; j < 4; ++j) {
            F4 col;
            #pragma unroll
            for (int i = 0; i < 4; ++i)
                col.f[i] = gelu_f(acc[i][j] + b1v.f[j]);
            *(float4*)&sM[c0 + j][e0] = col.v;
        }
        __syncthreads();

        // ---- GEMM2: [64e x 64] @ [64 x 64c] ----
        float acc2[4][4] = {};
        #pragma unroll 8
        for (int k = 0; k < 64; ++k) {
            F4 xv, wv;
            xv.v = *(const float4*)&sM[k][e0];
            wv.v = *(const float4*)&sW2[k][c0];
            #pragma unroll
            for (int i = 0; i < 4; ++i)
                #pragma unroll
                for (int j = 0; j < 4; ++j)
                    acc2[i][j] = fmaf(xv.f[i], wv.f[j], acc2[i][j]);
        }

        // ---- scatter-add ----
        #pragma unroll
        for (int i = 0; i < 4; ++i) {
            if (gbase + e0 + i < nE) {
                float* arow = agg + (size_t)sDst[e0 + i] * 64 + c0;
                #pragma unroll
                for (int j = 0; j < 4; ++j)
                    __hip_atomic_fetch_add(arow + j, acc2[i][j] + b2v.f[j],
                                           __ATOMIC_RELAXED, __HIP_MEMORY_SCOPE_AGENT);
            }
        }
        __syncthreads();   // protect sX/sM/sDst for next tile
    }
}

// ---------------- Kernel B: node update + LayerNorm + GELU + residual ----------------
__global__ __launch_bounds__(256) void node_update_kernel(
    const float* __restrict__ nf,   // [N,64]
    const float* agg,               // [N,64] (may alias out)
    const float* __restrict__ W3,   // [128,64]
    const float* __restrict__ b3,   // [64]
    const float* __restrict__ lns,  // [64]
    const float* __restrict__ lnb,  // [64]
    float* out, int nN)
{
    __shared__ float sW3[128][64];
    __shared__ float sU[128][TN + PADE];   // upd transposed [k][n]
    __shared__ float sP1[16][TN];
    __shared__ float sP2[16][TN];
    __shared__ float sMu[TN];
    __shared__ float sRs[TN];

    const int t = threadIdx.x;
    for (int i = t * 4; i < 128 * 64; i += 1024)
        *(float4*)((float*)sW3 + i) = *(const float4*)(W3 + i);

    const int lane = t & 63;
    const int w    = t >> 6;
    const int tb   = blockIdx.x * TN;
    const int node = tb + lane;
    const bool valid = node < nN;

    // stage upd = concat(nf, agg) transposed: wave w covers 32 k-rows
    {
        const float* base = (w < 2) ? (nf  + (size_t)node * 64 + w * 32)
                                    : (agg + (size_t)node * 64 + (w - 2) * 32);
        const int kb = (w < 2) ? (w * 32) : (64 + (w - 2) * 32);
        #pragma unroll
        for (int q = 0; q < 8; ++q) {
            F4 v;
            v.v = valid ? *(const float4*)(base + q * 4) : make_float4(0.f, 0.f, 0.f, 0.f);
            #pragma unroll
            for (int j = 0; j < 4; ++j)
                sU[kb + q * 4 + j][lane] = v.f[j];
        }
    }

    const int n0 = (t & 15) * 4;
    const int c0 = (t >> 4) * 4;
    F4 b3v, sv, bv;
    b3v.v = *(const float4*)(b3  + c0);
    sv.v  = *(const float4*)(lns + c0);
    bv.v  = *(const float4*)(lnb + c0);
    __syncthreads();

    float acc[4][4] = {};
    #pragma unroll 8
    for (int k = 0; k < 128; ++k) {
        F4 xv, wv;
        xv.v = *(const float4*)&sU[k][n0];
        wv.v = *(const float4*)&sW3[k][c0];
        #pragma unroll
        for (int i = 0; i < 4; ++i)
            #pragma unroll
            for (int j = 0; j < 4; ++j)
                acc[i][j] = fmaf(xv.f[i], wv.f[j], acc[i][j]);
    }

    float h[4][4];
    #pragma unroll
    for (int i = 0; i < 4; ++i)
        #pragma unroll
        for (int j = 0; j < 4; ++j)
            h[i][j] = acc[i][j] + b3v.f[j];

    // LN partial sums (this thread covers 4 channels of each of its 4 nodes)
    const int cg = t >> 4;
    #pragma unroll
    for (int i = 0; i < 4; ++i) {
        float s1 = h[i][0] + h[i][1] + h[i][2] + h[i][3];
        float s2 = h[i][0]*h[i][0] + h[i][1]*h[i][1] + h[i][2]*h[i][2] + h[i][3]*h[i][3];
        sP1[cg][n0 + i] = s1;
        sP2[cg][n0 + i] = s2;
    }
    __syncthreads();
    if (t < TN) {
        float m1 = 0.f, m2 = 0.f;
        #pragma unroll
        for (int g = 0; g < 16; ++g) { m1 += sP1[g][t]; m2 += sP2[g][t]; }
        float mu  = m1 * (1.f / 64.f);
        float var = m2 * (1.f / 64.f) - mu * mu;
        sMu[t] = mu;
        sRs[t] = rsqrtf(var + 1e-6f);
    }
    __syncthreads();

    #pragma unroll
    for (int i = 0; i < 4; ++i) {
        const int gnode = tb + n0 + i;
        const float mu = sMu[n0 + i];
        const float rs = sRs[n0 + i];
        if (gnode < nN) {
            #pragma unroll
            for (int j = 0; j < 4; ++j) {
                float xn = (h[i][j] - mu) * rs * sv.f[j] + bv.f[j];
                float r  = gelu_f(xn) + sU[c0 + j][n0 + i];   // + node_features residual
                out[(size_t)gnode * 64 + c0 + j] = r;
            }
        }
    }
}

extern "C" void kernel_launch(void* const* d_in, const int* in_sizes, int n_in,
                              void* d_out, int out_size, void* d_ws, size_t ws_size,
                              hipStream_t stream)
{
    const float* nf  = (const float*)d_in[0];
    const float* ef  = (const float*)d_in[1];
    const int*   ei  = (const int*)  d_in[2];
    const float* W1  = (const float*)d_in[3];
    const float* b1  = (const float*)d_in[4];
    const float* W2  = (const float*)d_in[5];
    const float* b2  = (const float*)d_in[6];
    const float* W3  = (const float*)d_in[7];
    const float* b3  = (const float*)d_in[8];
    const float* lns = (const float*)d_in[9];
    const float* lnb = (const float*)d_in[10];

    const int nN = in_sizes[0] / 64;
    const int nE = in_sizes[2] / 2;
    float* out = (float*)d_out;

    const size_t aggBytes = (size_t)nN * 64 * sizeof(float);
    float* agg = (ws_size >= aggBytes) ? (float*)d_ws : out;   // fallback: block-local RAW on out is safe

    hipMemsetAsync(agg, 0, aggBytes, stream);

    const int nTiles = (nE + TE - 1) / TE;
    const int gridA  = nTiles < 512 ? nTiles : 512;   // 2 blocks/CU resident (76KB LDS), grid-stride
    hipLaunchKernelGGL(edge_mlp_kernel, dim3(gridA), dim3(256), 0, stream,
                       nf, ef, ei, W1, b1, W2, b2, agg, nE, nTiles);

    const int gridB = (nN + TN - 1) / TN;
    hipLaunchKernelGGL(node_update_kernel, dim3(gridB), dim3(256), 0, stream,
                       nf, agg, W3, b3, lns, lnb, out, nN);
}